// Round 9
// baseline (277.901 us; speedup 1.0000x reference)
//
#include <hip/hip_runtime.h>
#include <hip/hip_bf16.h>

#define N_NODES 50000
#define N_EDGES 800000
#define NUM_GRAPHS 512
#define D 64
#define BN_EPS 1e-5f

#define BUK_SHIFT 7
#define BUK_SIZE 128
#define NBUK ((N_NODES + BUK_SIZE - 1) / BUK_SIZE)   // 391
#define CHUNK_A 4096
#define NBLK_A ((N_EDGES + CHUNK_A - 1) / CHUNK_A)   // 196
#define GBLK ((N_NODES + 63) / 64)                   // 782
#define SBLK 256                                     // bnstats blocks

// ---------------- zero: bucket counters + offs tail ----------------
__global__ __launch_bounds__(512) void k_zero(int* __restrict__ bcnt,
                                              int* __restrict__ offs) {
    int t = threadIdx.x;
    for (int j = t; j < NBUK; j += 512) bcnt[j] = 0;
    if (t == 0) offs[N_NODES] = N_EDGES;
}

// ---------------- bucket histogram (LDS-reduced) ----------------
__global__ __launch_bounds__(256) void k_bhist(const int* __restrict__ ei,
                                               int* __restrict__ bcnt) {
    __shared__ int h[NBUK];
    int t = threadIdx.x;
    for (int j = t; j < NBUK; j += 256) h[j] = 0;
    __syncthreads();
    int e0 = blockIdx.x * CHUNK_A;
#pragma unroll
    for (int i = 0; i < CHUNK_A / 256; i++) {
        int e = e0 + i * 256 + t;
        if (e < N_EDGES) atomicAdd(&h[ei[N_EDGES + e] >> BUK_SHIFT], 1);
    }
    __syncthreads();
    for (int j = t; j < NBUK; j += 256)
        if (h[j]) atomicAdd(&bcnt[j], h[j]);
}

// ---------------- exclusive scan of 391 bucket counts ----------------
__global__ __launch_bounds__(512) void k_bscan(const int* __restrict__ bcnt,
                                               int* __restrict__ boffs,
                                               int* __restrict__ gcur) {
    __shared__ int sm[512];
    int t = threadIdx.x;
    int v = (t < NBUK) ? bcnt[t] : 0;
    sm[t] = v;
    __syncthreads();
    for (int off = 1; off < 512; off <<= 1) {
        int a = sm[t];
        int u = (t >= off) ? sm[t - off] : 0;
        __syncthreads();
        sm[t] = a + u;
        __syncthreads();
    }
    if (t < NBUK) { int ex = sm[t] - v; boffs[t] = ex; gcur[t] = ex; }
    if (t == 0) boffs[NBUK] = N_EDGES;
}

// ---------------- pass A: bin edges into buckets, packed u32 (row<<16 | src) ----------------
__global__ __launch_bounds__(256) void k_binA(const int* __restrict__ ei,
                                              int* __restrict__ gcur,
                                              unsigned* __restrict__ pairs) {
    __shared__ int cnt[NBUK];
    __shared__ int base[NBUK];
    int t = threadIdx.x;
    for (int j = t; j < NBUK; j += 256) cnt[j] = 0;
    __syncthreads();
    int e0 = blockIdx.x * CHUNK_A;
    unsigned pd[CHUNK_A / 256];   // (d<<16)|s  (both < 2^16)
    int loc[CHUNK_A / 256];
#pragma unroll
    for (int i = 0; i < CHUNK_A / 256; i++) {
        int e = e0 + i * 256 + t;
        pd[i] = 0xFFFFFFFFu;
        if (e < N_EDGES) {
            unsigned s = (unsigned)ei[e];
            unsigned d = (unsigned)ei[N_EDGES + e];
            pd[i] = (d << 16) | s;
            loc[i] = atomicAdd(&cnt[d >> BUK_SHIFT], 1);
        }
    }
    __syncthreads();
    for (int j = t; j < NBUK; j += 256)
        base[j] = cnt[j] ? atomicAdd(&gcur[j], cnt[j]) : 0;
    __syncthreads();
#pragma unroll
    for (int i = 0; i < CHUNK_A / 256; i++) {
        if (pd[i] != 0xFFFFFFFFu) {
            unsigned d = pd[i] >> 16;
            pairs[base[d >> BUK_SHIFT] + loc[i]] =
                ((d & (BUK_SIZE - 1)) << 16) | (pd[i] & 0xFFFFu);
        }
    }
}

// ---------------- in-bucket counting sort -> CSR esrc + per-node offs ----------------
__global__ __launch_bounds__(256) void k_sort(const unsigned* __restrict__ pairs,
                                              const int* __restrict__ boffs,
                                              int* __restrict__ offs,
                                              int* __restrict__ esrc) {
    __shared__ int cnt[BUK_SIZE];
    __shared__ int sm[BUK_SIZE];
    __shared__ int cur[BUK_SIZE];
    int b = blockIdx.x, t = threadIdx.x;
    int n0 = b << BUK_SHIFT;
    int nrows = min(BUK_SIZE, N_NODES - n0);
    int e0 = boffs[b], e1 = boffs[b + 1];
    int m = e1 - e0;
    if (t < BUK_SIZE) cnt[t] = 0;
    __syncthreads();
    for (int j = t; j < m; j += 256)
        atomicAdd(&cnt[pairs[e0 + j] >> 16], 1);
    __syncthreads();
    if (t < BUK_SIZE) sm[t] = cnt[t];
    __syncthreads();
    for (int off = 1; off < BUK_SIZE; off <<= 1) {
        int v = 0, u = 0;
        if (t < BUK_SIZE) { v = sm[t]; u = (t >= off) ? sm[t - off] : 0; }
        __syncthreads();
        if (t < BUK_SIZE) sm[t] = v + u;
        __syncthreads();
    }
    if (t < BUK_SIZE) {
        int ex = sm[t] - cnt[t];
        cur[t] = ex;
        if (t < nrows) offs[n0 + t] = e0 + ex;
    }
    __syncthreads();
    for (int j = t; j < m; j += 256) {
        unsigned p = pairs[e0 + j];
        int pos = atomicAdd(&cur[p >> 16], 1);
        esrc[e0 + pos] = (int)(p & 0xFFFFu);
    }
}

// ---------------- gather-sum: agg[n] = x[n] + sum_{e: dst=n} x[src_e] ----------------
__global__ __launch_bounds__(256) void k_gather(const float* __restrict__ x,
                                                const int* __restrict__ offs,
                                                const int* __restrict__ esrc,
                                                float* __restrict__ agg) {
    int wid = (blockIdx.x * 256 + threadIdx.x) >> 6;
    int c = threadIdx.x & 63;
    if (wid >= N_NODES) return;
    int base = offs[wid];
    int end = offs[wid + 1];
    float acc = x[(size_t)wid * D + c];
    int i = base;
    for (; i + 3 < end; i += 4) {
        int s0 = esrc[i], s1 = esrc[i + 1], s2 = esrc[i + 2], s3 = esrc[i + 3];
        float v0 = x[(size_t)s0 * D + c];
        float v1 = x[(size_t)s1 * D + c];
        float v2 = x[(size_t)s2 * D + c];
        float v3 = x[(size_t)s3 * D + c];
        acc += v0; acc += v1; acc += v2; acc += v3;
    }
    for (; i < end; i++) acc += x[(size_t)esrc[i] * D + c];
    agg[(size_t)wid * D + c] = acc;
}

// ---------------- GEMM1: h[r][c] = agg[r][:] @ W1[:,c] + b1[c] (row-major out) ----
// block = 64 rows x 4 col-chunks; LDS tile [64][65] (pad: read bank=(lane+k)%32, 2-way=free)
__global__ __launch_bounds__(256) void k_gemm1(const float* __restrict__ agg,
                                               const float* __restrict__ W1,
                                               const float* __restrict__ b1,
                                               float* __restrict__ h) {
    __shared__ float xs[64][65];
    int blk = blockIdx.x, t = threadIdx.x;
    int r0 = blk * 64;
    const float4* a4 = (const float4*)(agg + (size_t)r0 * D);
    for (int i = t; i < 1024; i += 256) {        // coalesced 16 KB tile load
        float4 v = a4[i];                         // tail block reads into h region (allocated)
        int row = i >> 4, q = (i & 15) * 4;
        xs[row][q] = v.x; xs[row][q + 1] = v.y;
        xs[row][q + 2] = v.z; xs[row][q + 3] = v.w;
    }
    __syncthreads();
    int lane = t & 63, chunk = t >> 6;
    int r = r0 + lane;
    int c0 = chunk * 16;
    float acc[16];
#pragma unroll
    for (int j = 0; j < 16; j++) acc[j] = b1[c0 + j];
#pragma unroll 4
    for (int k = 0; k < D; k++) {
        float v = xs[lane][k];
#pragma unroll
        for (int j = 0; j < 16; j++)
            acc[j] += v * W1[k * D + c0 + j];     // wave-uniform -> scalar loads
    }
    if (r < N_NODES) {
        float* hp = h + (size_t)r * D + c0;
#pragma unroll
        for (int j4 = 0; j4 < 4; j4++) {
            float4 o;
            o.x = acc[j4 * 4]; o.y = acc[j4 * 4 + 1];
            o.z = acc[j4 * 4 + 2]; o.w = acc[j4 * 4 + 3];
            *(float4*)(hp + j4 * 4) = o;
        }
    }
}

// ---------------- BN stats: per-feature partial sums, no atomics ----------------
__global__ __launch_bounds__(256) void k_bnstats(const float* __restrict__ h,
                                                 float* __restrict__ partial) {
    int t = threadIdx.x, w = t >> 6, c = t & 63;
    float s = 0.f, q = 0.f;
    for (int n = blockIdx.x * 4 + w; n < N_NODES; n += SBLK * 4) {
        float v = h[(size_t)n * D + c];           // coalesced 256B per wave
        s += v; q += v * v;
    }
    __shared__ float shS[4][64], shQ[4][64];
    shS[w][c] = s; shQ[w][c] = q;
    __syncthreads();
    if (w == 0) {
        float ts = shS[0][c] + shS[1][c] + shS[2][c] + shS[3][c];
        float tq = shQ[0][c] + shQ[1][c] + shQ[2][c] + shQ[3][c];
        partial[blockIdx.x * 128 + c] = ts;
        partial[blockIdx.x * 128 + 64 + c] = tq;
    }
}

// ---------------- BN finalize: reduce partials, fold gamma/beta ----------------
__global__ __launch_bounds__(512) void k_bnfinal(const float* __restrict__ partial,
                                                 const float* __restrict__ gamma,
                                                 const float* __restrict__ beta,
                                                 float* __restrict__ bnscale,
                                                 float* __restrict__ bnshift) {
    __shared__ float sh[4][128];
    __shared__ float tot[128];
    int t = threadIdx.x, c = t & 127, sl = t >> 7;
    float s = 0.f;
    for (int b = sl; b < SBLK; b += 4) s += partial[b * 128 + c];
    sh[sl][c] = s;
    __syncthreads();
    if (t < 128) tot[t] = sh[0][t] + sh[1][t] + sh[2][t] + sh[3][t];
    __syncthreads();
    if (t < 64) {
        float mean = tot[t] * (1.0f / N_NODES);
        float var  = tot[64 + t] * (1.0f / N_NODES) - mean * mean;
        float rstd = rsqrtf(var + BN_EPS);
        float sc = gamma[t] * rstd;
        bnscale[t] = sc;
        bnshift[t] = beta[t] - mean * sc;
    }
}

// ---------------- GEMM2: h2 = relu( relu(bn(h)) @ W2 + b2 ), row-major ----------------
__global__ __launch_bounds__(256) void k_gemm2(const float* __restrict__ h,
                                               const float* __restrict__ bnscale,
                                               const float* __restrict__ bnshift,
                                               const float* __restrict__ W2,
                                               const float* __restrict__ b2,
                                               float* __restrict__ h2) {
    __shared__ float xs[64][65];
    __shared__ float bs[64], bb[64];
    int blk = blockIdx.x, t = threadIdx.x;
    if (t < 64) { bs[t] = bnscale[t]; bb[t] = bnshift[t]; }
    __syncthreads();
    int r0 = blk * 64;
    const float4* a4 = (const float4*)(h + (size_t)r0 * D);
    for (int i = t; i < 1024; i += 256) {
        float4 v = a4[i];
        int row = i >> 4, q = (i & 15) * 4;
        xs[row][q]     = fmaxf(v.x * bs[q]     + bb[q],     0.0f);   // bn+relu fused on load
        xs[row][q + 1] = fmaxf(v.y * bs[q + 1] + bb[q + 1], 0.0f);
        xs[row][q + 2] = fmaxf(v.z * bs[q + 2] + bb[q + 2], 0.0f);
        xs[row][q + 3] = fmaxf(v.w * bs[q + 3] + bb[q + 3], 0.0f);
    }
    __syncthreads();
    int lane = t & 63, chunk = t >> 6;
    int r = r0 + lane;
    int c0 = chunk * 16;
    float acc[16];
#pragma unroll
    for (int j = 0; j < 16; j++) acc[j] = b2[c0 + j];
#pragma unroll 4
    for (int k = 0; k < D; k++) {
        float v = xs[lane][k];
#pragma unroll
        for (int j = 0; j < 16; j++)
            acc[j] += v * W2[k * D + c0 + j];
    }
    if (r < N_NODES) {
        float* hp = h2 + (size_t)r * D + c0;
#pragma unroll
        for (int j4 = 0; j4 < 4; j4++) {
            float4 o;
            o.x = fmaxf(acc[j4 * 4], 0.0f);     o.y = fmaxf(acc[j4 * 4 + 1], 0.0f);
            o.z = fmaxf(acc[j4 * 4 + 2], 0.0f); o.w = fmaxf(acc[j4 * 4 + 3], 0.0f);
            *(float4*)(hp + j4 * 4) = o;
        }
    }
}

// ---------------- pooling: per-graph add & max, row-major h2, 4 waves/graph ----------------
__device__ __forceinline__ int lower_bound(const int* __restrict__ b, int v) {
    int lo = 0, hi = N_NODES;
    while (lo < hi) {
        int m = (lo + hi) >> 1;
        if (b[m] < v) lo = m + 1; else hi = m;
    }
    return lo;
}

__global__ __launch_bounds__(256) void k_pool(const float* __restrict__ h2,
                                              const int* __restrict__ batch,
                                              float* __restrict__ g) {
    int gi = blockIdx.x, t = threadIdx.x, w = t >> 6, c = t & 63;
    int s0 = lower_bound(batch, gi);
    int s1 = lower_bound(batch, gi + 1);
    float sm = 0.f, mx = 0.f;                     // post-ReLU >= 0, 0-init max exact
    for (int n = s0 + w; n < s1; n += 4) {
        float v = h2[(size_t)n * D + c];          // coalesced 256B per wave
        sm += v; mx = fmaxf(mx, v);
    }
    __shared__ float shS[4][64], shM[4][64];
    shS[w][c] = sm; shM[w][c] = mx;
    __syncthreads();
    if (w == 0) {
        float ts = shS[0][c] + shS[1][c] + shS[2][c] + shS[3][c];
        float tm = fmaxf(fmaxf(shM[0][c], shM[1][c]), fmaxf(shM[2][c], shM[3][c]));
        g[gi * 128 + c] = ts;
        g[gi * 128 + 64 + c] = tm;
    }
}

// ---------------- head ----------------
__global__ __launch_bounds__(128) void k_head(const float* __restrict__ g,
                                              const float* __restrict__ Wl1,
                                              const float* __restrict__ bl1,
                                              const float* __restrict__ Wl2,
                                              const float* __restrict__ bl2,
                                              float* __restrict__ out) {
    __shared__ float gv[128];
    __shared__ float red[2];
    int gi = blockIdx.x;
    int t = threadIdx.x;
    gv[t] = g[gi * 128 + t];
    __syncthreads();
    float acc = bl1[t];
#pragma unroll
    for (int k = 0; k < 128; k++)
        acc += gv[k] * Wl1[k * 128 + t];
    acc = fmaxf(acc, 0.0f);
    float part = acc * Wl2[t];
    for (int off = 32; off; off >>= 1) part += __shfl_down(part, off);
    if ((t & 63) == 0) red[t >> 6] = part;
    __syncthreads();
    if (t == 0) {
        float logit = red[0] + red[1] + bl2[0];
        out[gi] = 1.0f / (1.0f + expf(-logit));
        out[NUM_GRAPHS + gi] = logit;
    }
}

extern "C" void kernel_launch(void* const* d_in, const int* in_sizes, int n_in,
                              void* d_out, int out_size, void* d_ws, size_t ws_size,
                              hipStream_t stream) {
    const float* x     = (const float*)d_in[0];
    const int*   ei    = (const int*)d_in[1];
    const int*   batch = (const int*)d_in[2];
    const float* W1    = (const float*)d_in[3];
    const float* b1    = (const float*)d_in[4];
    const float* gamma = (const float*)d_in[5];
    const float* beta  = (const float*)d_in[6];
    const float* W2    = (const float*)d_in[7];
    const float* b2    = (const float*)d_in[8];
    const float* Wl1   = (const float*)d_in[9];
    const float* bl1   = (const float*)d_in[10];
    const float* Wl2   = (const float*)d_in[11];
    const float* bl2   = (const float*)d_in[12];
    float* out = (float*)d_out;

    float* ws = (float*)d_ws;
    float* agg    = ws;                          // [N][64] row-major
    float* h      = agg + (size_t)N_NODES * D;   // [N][64] row-major
    float* gbuf   = h + (size_t)N_NODES * D;     // [512][128]
    float* bnscale= gbuf + NUM_GRAPHS * 128;     // 64
    float* bnshift= bnscale + 64;                // 64
    int*   bcnt   = (int*)(bnshift + 64);        // [NBUK]
    int*   boffs  = bcnt + NBUK;                 // [NBUK+1]
    int*   gcur   = boffs + NBUK + 1;            // [NBUK]
    int*   offs   = gcur + NBUK;                 // [N+1]
    int*   esrc   = offs + N_NODES + 1;          // [E]
    float* partial= (float*)(esrc + N_EDGES);    // [SBLK*128]
    unsigned* pairs = (unsigned*)h;              // alias: pairs dead before gemm1 writes h
    float* h2     = agg;                         // alias: agg dead after gemm1

    k_zero   <<<1, 512, 0, stream>>>(bcnt, offs);
    k_bhist  <<<NBLK_A, 256, 0, stream>>>(ei, bcnt);
    k_bscan  <<<1, 512, 0, stream>>>(bcnt, boffs, gcur);
    k_binA   <<<NBLK_A, 256, 0, stream>>>(ei, gcur, pairs);
    k_sort   <<<NBUK, 256, 0, stream>>>(pairs, boffs, offs, esrc);
    k_gather <<<(N_NODES * 64 + 255) / 256, 256, 0, stream>>>(x, offs, esrc, agg);
    k_gemm1  <<<GBLK, 256, 0, stream>>>(agg, W1, b1, h);
    k_bnstats<<<SBLK, 256, 0, stream>>>(h, partial);
    k_bnfinal<<<1, 512, 0, stream>>>(partial, gamma, beta, bnscale, bnshift);
    k_gemm2  <<<GBLK, 256, 0, stream>>>(h, bnscale, bnshift, W2, b2, h2);
    k_pool   <<<NUM_GRAPHS, 256, 0, stream>>>(h2, batch, gbuf);
    k_head   <<<NUM_GRAPHS, 128, 0, stream>>>(gbuf, Wl1, bl1, Wl2, bl2, out);
}